// Round 4
// baseline (134.044 us; speedup 1.0000x reference)
//
#include <hip/hip_runtime.h>
#include <cstdint>

#define NBATCH 4
#define NPATCH 4096
#define MAXC   5
#define NCHUNK 6                            /* col chunks per (batch, rowgroup) */
#define RGROUPS 128                         /* 32-row groups per batch */
#define GRID_MAIN (NBATCH * RGROUPS * NCHUNK)   /* 3072 one-wave blocks */
#define SCALE  14.285714285714286f          /* 1/T, T=0.07 */
#define SCALE2 20.609929006188747f          /* (1/T) * log2(e) */
#define LN2F   0.6931471805599453f
#define NEGH  -1.0e38f
#define NEGFILL_T -142.85714285714286f      /* NEG_FILL / T */
#define NROWS (NBATCH * NPATCH)

typedef __attribute__((ext_vector_type(8))) short short8;   // 8 bf16 (4 VGPRs)
typedef __attribute__((ext_vector_type(4))) float f32x4;

__device__ __forceinline__ float fexp2(float x) { return __builtin_amdgcn_exp2f(x); }
__device__ __forceinline__ float flog2(float x) { return __builtin_amdgcn_logf(x); }  // v_log_f32 = log2

__device__ __forceinline__ unsigned short f2bf(float f) {
  uint32_t u = __builtin_bit_cast(uint32_t, f);
  u = (u + 0x7FFFu + ((u >> 16) & 1u)) >> 16;   // RNE
  return (unsigned short)u;
}

// Fragment layout (srcb and tgtb): tile = 16 rows x 256 k (8 KB).
// 16B chunk (8 bf16, one row's k-octet) at uint4 index  tile*512 + kc*16 + row16
// (kc = k/8, row16 = row%16).  A wave's fragment load (kc = ks*4+q, row = l4,
// lane = q*16+l4) is  base + ks*64 + lane : one fully-coalesced 1KB transaction.

// ---- k_aux: 2 roles ----  (unchanged from R2)
__global__ __launch_bounds__(256) void k_aux(const float* __restrict__ src,
                                             const float* __restrict__ tgt,
                                             const int* __restrict__ classes,
                                             unsigned short* __restrict__ tgtb,
                                             unsigned short* __restrict__ srcb,
                                             float* __restrict__ pos,
                                             int* __restrict__ outpos,
                                             int* __restrict__ counts) {
  int blk = blockIdx.x;
  if (blk < 512) {
    int t  = threadIdx.x;
    int tl = blk * 2 + (t >> 7);
    int tt = t & 127;
    int row16 = tt >> 3;
    int kg    = tt & 7;
    size_t rowbase = (size_t)(tl * 16 + row16) * 256 + kg * 32;
    const float4* rs = (const float4*)(src + rowbase);
    const float4* rt_ = (const float4*)(tgt + rowbase);
    uint4* wsrc = (uint4*)srcb + (size_t)tl * 512 + (size_t)(kg * 4) * 16 + row16;
    uint4* wtgt = (uint4*)tgtb + (size_t)tl * 512 + (size_t)(kg * 4) * 16 + row16;
    float d = 0.f;
#pragma unroll
    for (int j = 0; j < 4; ++j) {
      float4 sa = rs[j * 2], sb = rs[j * 2 + 1];
      float4 ta = rt_[j * 2], tb = rt_[j * 2 + 1];
      d += sa.x * ta.x + sa.y * ta.y + sa.z * ta.z + sa.w * ta.w
         + sb.x * tb.x + sb.y * tb.y + sb.z * tb.z + sb.w * tb.w;
      union { ushort4 h[2]; uint4 u; } pk;
      pk.h[0].x = f2bf(sa.x * SCALE2); pk.h[0].y = f2bf(sa.y * SCALE2);
      pk.h[0].z = f2bf(sa.z * SCALE2); pk.h[0].w = f2bf(sa.w * SCALE2);
      pk.h[1].x = f2bf(sb.x * SCALE2); pk.h[1].y = f2bf(sb.y * SCALE2);
      pk.h[1].z = f2bf(sb.z * SCALE2); pk.h[1].w = f2bf(sb.w * SCALE2);
      wsrc[j * 16] = pk.u;
      pk.h[0].x = f2bf(ta.x); pk.h[0].y = f2bf(ta.y);
      pk.h[0].z = f2bf(ta.z); pk.h[0].w = f2bf(ta.w);
      pk.h[1].x = f2bf(tb.x); pk.h[1].y = f2bf(tb.y);
      pk.h[1].z = f2bf(tb.z); pk.h[1].w = f2bf(tb.w);
      wtgt[j * 16] = pk.u;
    }
    d += __shfl_xor(d, 1, 64);
    d += __shfl_xor(d, 2, 64);
    d += __shfl_xor(d, 4, 64);
    if (kg == 0) pos[tl * 16 + row16] = d * SCALE;
    return;
  }

  __shared__ int sa[MAXC * 256];
  __shared__ int sb2[MAXC * 256];
  int b = blk - 512, t = threadIdx.x;
  int base = b * NPATCH + t * 16;
  int cv[16];
#pragma unroll
  for (int e = 0; e < 16; ++e) cv[e] = classes[base + e];
  int cnt[MAXC];
#pragma unroll
  for (int c = 0; c < MAXC; ++c) {
    cnt[c] = 0;
#pragma unroll
    for (int e = 0; e < 16; ++e)
      if (cv[e] == c) cnt[c]++;
  }
#pragma unroll
  for (int c = 0; c < MAXC; ++c) sa[c * 256 + t] = cnt[c];
  __syncthreads();

  int* rp = sa; int* wp = sb2;
  for (int d = 1; d < 256; d <<= 1) {
#pragma unroll
    for (int c = 0; c < MAXC; ++c) {
      int v = rp[c * 256 + t];
      if (t >= d) v += rp[c * 256 + t - d];
      wp[c * 256 + t] = v;
    }
    __syncthreads();
    int* tmp = rp; rp = wp; wp = tmp;
  }

  int tot[MAXC], excl[MAXC], off[MAXC + 1];
  off[0] = 0;
#pragma unroll
  for (int c = 0; c < MAXC; ++c) {
    tot[c]  = rp[c * 256 + 255];
    excl[c] = rp[c * 256 + t] - cnt[c];
    off[c + 1] = off[c] + tot[c];
  }
#pragma unroll
  for (int c = 0; c < MAXC; ++c) {
    int r = off[c] + excl[c];
#pragma unroll
    for (int e = 0; e < 16; ++e)
      if (cv[e] == c) { outpos[base + e] = r; r++; }
  }
  if (t < MAXC) counts[b * MAXC + t] = tot[t];
}

// ---------------- main fused GEMM + online lse stats -----------------------------------
// R3: VALU-issue diet.  R2 showed dur invariant to packing (R1==R2, FETCH halved, no
// time change): limiter = per-SIMD issue work (VALU 43% + MFMA 27%).  Changes:
//  (1) accA/accB 2-tile ping-pong kills the 16-mov pacc copy per iter,
//  (2) defer-rescale fast path (wave-uniform __any gate on RAW acc max; bit-exact,
//      skips 8 rescale-exp2 + fmax + fma per iter in steady state),
//  (3) s_setprio(1) around MFMA clusters (independent-wave regime: T5-positive).
__global__ __launch_bounds__(64) void k_main(const unsigned short* __restrict__ srcb,
                                             const unsigned short* __restrict__ tgtb,
                                             const int* __restrict__ classes,
                                             float* __restrict__ pm,
                                             float* __restrict__ ps) {
  const int phys = blockIdx.x;
  const int lid  = (phys & 7) * (GRID_MAIN / 8) + (phys >> 3);
  const int b   = lid / (RGROUPS * NCHUNK);
  const int r2  = lid % (RGROUPS * NCHUNK);
  const int rg  = r2 / NCHUNK;
  const int j   = r2 % NCHUNK;
  const int t0  = (j * 64) / 3;               // 32-col tile range [t0, t1) of 128
  const int t1  = ((j + 1) * 64) / 3;         // chunks: 21,21,22,21,21,22
  const int lane = threadIdx.x;
  const int q = lane >> 4, l4 = lane & 15;
  const int rowstart = b * NPATCH + rg * 32;

  // ---- A fragments: 32 rows resident (16 coalesced uint4 loads)
  const uint4* ap = (const uint4*)srcb + (size_t)(b * 256 + rg * 2) * 512 + lane;
  uint4 afr[2][8];
#pragma unroll
  for (int rt = 0; rt < 2; ++rt)
#pragma unroll
    for (int ks = 0; ks < 8; ++ks)
      afr[rt][ks] = ap[rt * 512 + ks * 64];

  int rcls[2][4];
#pragma unroll
  for (int rt = 0; rt < 2; ++rt)
#pragma unroll
    for (int r = 0; r < 4; ++r)
      rcls[rt][r] = classes[rowstart + rt * 16 + q * 4 + r];

  float m_[2][4], s_[2][4];
#pragma unroll
  for (int rt = 0; rt < 2; ++rt)
#pragma unroll
    for (int r = 0; r < 4; ++r) { m_[rt][r] = -INFINITY; s_[rt][r] = 0.f; }

  const uint4* bp = (const uint4*)tgtb + (size_t)(b * 256 + t0 * 2) * 512 + lane;
  const int* clp  = classes + b * NPATCH + t0 * 32 + l4;

  uint4 ea0[4], ea1[4], eb0[4], eb1[4];
#define LOADH(d0, d1, uoff)                                                         \
  {                                                                                 \
    _Pragma("unroll")                                                               \
    for (int i = 0; i < 4; ++i) {                                                   \
      d0[i] = bp[(uoff) + i * 64];                                                  \
      d1[i] = bp[(uoff) + i * 64 + 512];                                            \
    }                                                                               \
  }

  // STATS with defer-rescale: gate on RAW (unmasked) acc vs running max.  Raw >= masked
  // so a false 'fast' is impossible; false 'full' (masked col was the max) is rare and
  // exact anyway.  Fast path: s += exp2(y-m) (masked y=NEGH underflows to +0 exactly).
  // First call always takes full path (m = -inf < finite raw max) -> m finite after.
#define STATS(ac, cc0, cc1)                                                         \
  {                                                                                 \
    int up = 0;                                                                     \
    _Pragma("unroll")                                                               \
    for (int rt = 0; rt < 2; ++rt) {                                                \
      _Pragma("unroll")                                                             \
      for (int r = 0; r < 4; ++r)                                                   \
        up |= (fmaxf((ac)[rt][0][r], (ac)[rt][1][r]) > m_[rt][r]) ? 1 : 0;          \
    }                                                                               \
    if (__any(up)) {                                                                \
      _Pragma("unroll")                                                             \
      for (int rt = 0; rt < 2; ++rt) {                                              \
        _Pragma("unroll")                                                           \
        for (int r = 0; r < 4; ++r) {                                               \
          int rc = rcls[rt][r];                                                     \
          float y0 = ((cc0) == rc) ? NEGH : (ac)[rt][0][r];                         \
          float y1 = ((cc1) == rc) ? NEGH : (ac)[rt][1][r];                         \
          float nm = fmaxf(m_[rt][r], fmaxf(y0, y1));                               \
          float e01 = fexp2(y0 - nm) + fexp2(y1 - nm);                              \
          s_[rt][r] = fmaf(s_[rt][r], fexp2(m_[rt][r] - nm), e01);                  \
          m_[rt][r] = nm;                                                           \
        }                                                                           \
      }                                                                             \
    } else {                                                                        \
      _Pragma("unroll")                                                             \
      for (int rt = 0; rt < 2; ++rt) {                                              \
        _Pragma("unroll")                                                           \
        for (int r = 0; r < 4; ++r) {                                               \
          int rc = rcls[rt][r];                                                     \
          float y0 = ((cc0) == rc) ? NEGH : (ac)[rt][0][r];                         \
          float y1 = ((cc1) == rc) ? NEGH : (ac)[rt][1][r];                         \
          s_[rt][r] += fexp2(y0 - m_[rt][r]) + fexp2(y1 - m_[rt][r]);               \
        }                                                                           \
      }                                                                             \
    }                                                                               \
  }

#define MM_KH0(CUR)                                                                 \
  {                                                                                 \
    __builtin_amdgcn_s_setprio(1);                                                  \
    _Pragma("unroll")                                                               \
    for (int ksl = 0; ksl < 4; ++ksl) {                                             \
      short8 b0 = __builtin_bit_cast(short8, ea0[ksl]);                             \
      short8 b1 = __builtin_bit_cast(short8, ea1[ksl]);                             \
      _Pragma("unroll")                                                             \
      for (int rt = 0; rt < 2; ++rt) {                                              \
        short8 a = __builtin_bit_cast(short8, afr[rt][ksl]);                        \
        CUR[rt][0] = __builtin_amdgcn_mfma_f32_16x16x32_bf16(                       \
            a, b0, (ksl == 0) ? zc : CUR[rt][0], 0, 0, 0);                          \
        CUR[rt][1] = __builtin_amdgcn_mfma_f32_16x16x32_bf16(                       \
            a, b1, (ksl == 0) ? zc : CUR[rt][1], 0, 0, 0);                          \
      }                                                                             \
    }                                                                               \
    __builtin_amdgcn_s_setprio(0);                                                  \
  }

#define MM_KH1(CUR)                                                                 \
  {                                                                                 \
    __builtin_amdgcn_s_setprio(1);                                                  \
    _Pragma("unroll")                                                               \
    for (int ksl = 0; ksl < 4; ++ksl) {                                             \
      short8 b0 = __builtin_bit_cast(short8, eb0[ksl]);                             \
      short8 b1 = __builtin_bit_cast(short8, eb1[ksl]);                             \
      _Pragma("unroll")                                                             \
      for (int rt = 0; rt < 2; ++rt) {                                              \
        short8 a = __builtin_bit_cast(short8, afr[rt][4 + ksl]);                    \
        CUR[rt][0] = __builtin_amdgcn_mfma_f32_16x16x32_bf16(a, b0, CUR[rt][0], 0, 0, 0); \
        CUR[rt][1] = __builtin_amdgcn_mfma_f32_16x16x32_bf16(a, b1, CUR[rt][1], 0, 0, 0); \
      }                                                                             \
    }                                                                               \
    __builtin_amdgcn_s_setprio(0);                                                  \
  }

  // BODY: process current tile into CUR acc; STATS on PRV acc between the two
  // prefetches (covers load latency with VALU); advance pointers.
#define BODY(CUR, PRV, MORE)                                                        \
  {                                                                                 \
    LOADH(eb0, eb1, 256);                                                           \
    int nc0 = clp[0];                                                               \
    int nc1 = clp[16];                                                              \
    MM_KH0(CUR);                                                                    \
    if (MORE) LOADH(ea0, ea1, 1024);                                                \
    STATS(PRV, pc0, pc1);                                                           \
    MM_KH1(CUR);                                                                    \
    pc0 = nc0; pc1 = nc1;                                                           \
    bp += 1024; clp += 32;                                                          \
  }

  LOADH(ea0, ea1, 0);                          // prologue: (t0, kh0)

  const f32x4 zc = {0.f, 0.f, 0.f, 0.f};
  f32x4 accA[2][2], accB[2][2];
  int pc0, pc1;
  const int nt = t1 - t0;                      // 21 or 22

  // ---- prologue: tile 0 -> accA (no stats yet)
  {
    LOADH(eb0, eb1, 256);
    pc0 = clp[0];
    pc1 = clp[16];
    MM_KH0(accA);
    LOADH(ea0, ea1, 1024);                     // nt >= 2 always
    MM_KH1(accA);
    bp += 1024; clp += 32;
  }

  int it = 1;
  for (; it + 1 < nt; it += 2) {
    BODY(accB, accA, true);                    // tile it   (next tile it+1 exists)
    BODY(accA, accB, (it + 2 < nt));           // tile it+1 (prefetch iff it+2 exists)
  }
  if (it < nt) {                               // one leftover tile (nt even)
    BODY(accB, accA, false);
    STATS(accB, pc0, pc1);
  } else {                                     // nt odd: last tile landed in accA
    STATS(accA, pc0, pc1);
  }
#undef LOADH
#undef STATS
#undef MM_KH0
#undef MM_KH1
#undef BODY

  // butterfly merge across the 16 col-lanes of each quad
#pragma unroll
  for (int off = 1; off < 16; off <<= 1) {
#pragma unroll
    for (int rt = 0; rt < 2; ++rt)
#pragma unroll
      for (int r = 0; r < 4; ++r) {
        float om = __shfl_xor(m_[rt][r], off, 64);
        float os = __shfl_xor(s_[rt][r], off, 64);
        float nm = fmaxf(m_[rt][r], om);
        s_[rt][r] = s_[rt][r] * fexp2(m_[rt][r] - nm) + os * fexp2(om - nm);
        m_[rt][r] = nm;
      }
  }

  if (l4 == 0) {
#pragma unroll
    for (int rt = 0; rt < 2; ++rt)
#pragma unroll
      for (int r = 0; r < 4; ++r) {
        size_t o = (size_t)j * NROWS + rowstart + rt * 16 + q * 4 + r;
        pm[o] = m_[rt][r];                     // log2 domain
        ps[o] = s_[rt][r];
      }
  }
}

// ---------------- final: merge chunk partials + pad term + scatter (grid 64) ----------
__global__ __launch_bounds__(256) void k_fin(const int* __restrict__ classes,
                                             const float* __restrict__ pos,
                                             const float* __restrict__ pm,
                                             const float* __restrict__ ps,
                                             const int* __restrict__ outpos,
                                             const int* __restrict__ counts,
                                             float* __restrict__ out) {
  int n = blockIdx.x * 256 + threadIdx.x;
  int b = n >> 12;
  int c = classes[n];
  float ps_ = pos[n];

  float M2 = -INFINITY;
  float mm[NCHUNK], ss[NCHUNK];
#pragma unroll
  for (int s = 0; s < NCHUNK; ++s) {
    mm[s] = pm[(size_t)s * NROWS + n];
    ss[s] = ps[(size_t)s * NROWS + n];
    M2 = fmaxf(M2, mm[s]);
  }
  float S2 = 0.f;
#pragma unroll
  for (int s = 0; s < NCHUNK; ++s) S2 = fmaf(ss[s], fexp2(mm[s] - M2), S2);
  float ln = (S2 > 0.f) ? (M2 + flog2(S2)) * LN2F : -INFINITY;

  int npad = counts[b * MAXC + c] - 1;
  float pt = (npad > 0) ? (logf((float)npad) + NEGFILL_T) : -INFINITY;
  float M = fmaxf(ps_, fmaxf(ln, pt));
  float lse = M + logf(expf(ps_ - M) + expf(ln - M) + expf(pt - M));
  out[b * NPATCH + outpos[n]] = lse - ps_;
}

extern "C" void kernel_launch(void* const* d_in, const int* in_sizes, int n_in,
                              void* d_out, int out_size, void* d_ws, size_t ws_size,
                              hipStream_t stream) {
  const float* src = (const float*)d_in[0];
  const float* tgt = (const float*)d_in[1];
  const int* cls   = (const int*)d_in[2];
  float* out = (float*)d_out;

  char* ws = (char*)d_ws;
  unsigned short* tgtb = (unsigned short*)(ws);            //  8,388,608 B (fragment layout)
  unsigned short* srcb = (unsigned short*)(ws + 8388608);  //  8,388,608 B (frag, pre-scaled)
  float* pos    = (float*)(ws + 16777216);                 //     65,536 B
  float* pm     = (float*)(ws + 16842752);                 //    393,216 B (6 chunk planes)
  float* ps     = (float*)(ws + 17235968);                 //    393,216 B
  int*   outpos = (int*)  (ws + 17629184);                 //     65,536 B
  int*   counts = (int*)  (ws + 17694720);                 //         80 B

  k_aux<<<512 + NBATCH, 256, 0, stream>>>(src, tgt, cls, tgtb, srcb, pos, outpos, counts);
  k_main<<<GRID_MAIN, 64, 0, stream>>>(srcb, tgtb, cls, pm, ps);
  k_fin<<<NROWS / 256, 256, 0, stream>>>(cls, pos, pm, ps, outpos, counts, out);
}

// Round 5
// 127.884 us; speedup vs baseline: 1.0482x; 1.0482x over previous
//
#include <hip/hip_runtime.h>
#include <cstdint>

#define NBATCH 4
#define NPATCH 4096
#define MAXC   5
#define NCHUNK 6                            /* col chunks (j) */
#define RBLOCKS 32                          /* 128-row blocks per batch */
#define GRID_MAIN (NBATCH * RBLOCKS * NCHUNK)   /* 768 4-wave blocks = 3/CU */
#define SCALE  14.285714285714286f          /* 1/T, T=0.07 */
#define SCALE2 20.609929006188747f          /* (1/T) * log2(e) */
#define LN2F   0.6931471805599453f
#define NEGH  -1.0e38f
#define NEGFILL_T -142.85714285714286f      /* NEG_FILL / T */
#define NROWS (NBATCH * NPATCH)

typedef __attribute__((ext_vector_type(8))) short short8;   // 8 bf16 (4 VGPRs)
typedef __attribute__((ext_vector_type(4))) float f32x4;

__device__ __forceinline__ float fexp2(float x) { return __builtin_amdgcn_exp2f(x); }
__device__ __forceinline__ float flog2(float x) { return __builtin_amdgcn_logf(x); }  // v_log_f32 = log2

__device__ __forceinline__ unsigned short f2bf(float f) {
  uint32_t u = __builtin_bit_cast(uint32_t, f);
  u = (u + 0x7FFFu + ((u >> 16) & 1u)) >> 16;   // RNE
  return (unsigned short)u;
}

// async global->LDS, 16B per lane; LDS dest is wave-uniform base + lane*16
__device__ __forceinline__ void glds16(const uint4* g, uint4* l) {
  __builtin_amdgcn_global_load_lds(
      (const __attribute__((address_space(1))) uint32_t*)g,
      (__attribute__((address_space(3))) uint32_t*)l, 16, 0, 0);
}

// Fragment layout (srcb and tgtb): tile = 16 rows x 256 k (8 KB).
// 16B chunk (8 bf16, one row's k-octet) at uint4 index  tile*512 + kc*16 + row16
// (kc = k/8, row16 = row%16).  A wave's fragment read (kc = ks*4+q, row = l4,
// lane = q*16+l4) is  base + ks*64 + lane : contiguous 1KB per instruction.

// ---- k_aux: 2 roles ----  (unchanged)
__global__ __launch_bounds__(256) void k_aux(const float* __restrict__ src,
                                             const float* __restrict__ tgt,
                                             const int* __restrict__ classes,
                                             unsigned short* __restrict__ tgtb,
                                             unsigned short* __restrict__ srcb,
                                             float* __restrict__ pos,
                                             int* __restrict__ outpos,
                                             int* __restrict__ counts) {
  int blk = blockIdx.x;
  if (blk < 512) {
    int t  = threadIdx.x;
    int tl = blk * 2 + (t >> 7);
    int tt = t & 127;
    int row16 = tt >> 3;
    int kg    = tt & 7;
    size_t rowbase = (size_t)(tl * 16 + row16) * 256 + kg * 32;
    const float4* rs = (const float4*)(src + rowbase);
    const float4* rt_ = (const float4*)(tgt + rowbase);
    uint4* wsrc = (uint4*)srcb + (size_t)tl * 512 + (size_t)(kg * 4) * 16 + row16;
    uint4* wtgt = (uint4*)tgtb + (size_t)tl * 512 + (size_t)(kg * 4) * 16 + row16;
    float d = 0.f;
#pragma unroll
    for (int j = 0; j < 4; ++j) {
      float4 sa = rs[j * 2], sb = rs[j * 2 + 1];
      float4 ta = rt_[j * 2], tb = rt_[j * 2 + 1];
      d += sa.x * ta.x + sa.y * ta.y + sa.z * ta.z + sa.w * ta.w
         + sb.x * tb.x + sb.y * tb.y + sb.z * tb.z + sb.w * tb.w;
      union { ushort4 h[2]; uint4 u; } pk;
      pk.h[0].x = f2bf(sa.x * SCALE2); pk.h[0].y = f2bf(sa.y * SCALE2);
      pk.h[0].z = f2bf(sa.z * SCALE2); pk.h[0].w = f2bf(sa.w * SCALE2);
      pk.h[1].x = f2bf(sb.x * SCALE2); pk.h[1].y = f2bf(sb.y * SCALE2);
      pk.h[1].z = f2bf(sb.z * SCALE2); pk.h[1].w = f2bf(sb.w * SCALE2);
      wsrc[j * 16] = pk.u;
      pk.h[0].x = f2bf(ta.x); pk.h[0].y = f2bf(ta.y);
      pk.h[0].z = f2bf(ta.z); pk.h[0].w = f2bf(ta.w);
      pk.h[1].x = f2bf(tb.x); pk.h[1].y = f2bf(tb.y);
      pk.h[1].z = f2bf(tb.z); pk.h[1].w = f2bf(tb.w);
      wtgt[j * 16] = pk.u;
    }
    d += __shfl_xor(d, 1, 64);
    d += __shfl_xor(d, 2, 64);
    d += __shfl_xor(d, 4, 64);
    if (kg == 0) pos[tl * 16 + row16] = d * SCALE;
    return;
  }

  __shared__ int sa[MAXC * 256];
  __shared__ int sb2[MAXC * 256];
  int b = blk - 512, t = threadIdx.x;
  int base = b * NPATCH + t * 16;
  int cv[16];
#pragma unroll
  for (int e = 0; e < 16; ++e) cv[e] = classes[base + e];
  int cnt[MAXC];
#pragma unroll
  for (int c = 0; c < MAXC; ++c) {
    cnt[c] = 0;
#pragma unroll
    for (int e = 0; e < 16; ++e)
      if (cv[e] == c) cnt[c]++;
  }
#pragma unroll
  for (int c = 0; c < MAXC; ++c) sa[c * 256 + t] = cnt[c];
  __syncthreads();

  int* rp = sa; int* wp = sb2;
  for (int d = 1; d < 256; d <<= 1) {
#pragma unroll
    for (int c = 0; c < MAXC; ++c) {
      int v = rp[c * 256 + t];
      if (t >= d) v += rp[c * 256 + t - d];
      wp[c * 256 + t] = v;
    }
    __syncthreads();
    int* tmp = rp; rp = wp; wp = tmp;
  }

  int tot[MAXC], excl[MAXC], off[MAXC + 1];
  off[0] = 0;
#pragma unroll
  for (int c = 0; c < MAXC; ++c) {
    tot[c]  = rp[c * 256 + 255];
    excl[c] = rp[c * 256 + t] - cnt[c];
    off[c + 1] = off[c] + tot[c];
  }
#pragma unroll
  for (int c = 0; c < MAXC; ++c) {
    int r = off[c] + excl[c];
#pragma unroll
    for (int e = 0; e < 16; ++e)
      if (cv[e] == c) { outpos[base + e] = r; r++; }
  }
  if (t < MAXC) counts[b * MAXC + t] = tot[t];
}

// ---------------- main fused GEMM + online lse stats -----------------------------------
// R4: LDS-shared B.  Evidence (R1==R2==R3 at 51-53us across wildly different occupancy/
// VALU configs; 1.07GB of per-wave B loads / ~20TB/s TCP return == measured time):
// k_main is bound by per-CU vector-load return bandwidth, NOT VALU/MFMA/occupancy.
// Fix: 4-wave blocks (4 rowgroups x same col chunk); B tile (16KB) staged ONCE per
// block into double-buffered LDS via global_load_lds (4 x dwordx4/wave), consumed by
// all 4 waves via conflict-free contiguous ds_read_b128 (LDS pipe).  TCP traffic /4.
// Stage t+1 at iter top; __syncthreads at iter end (its vmcnt(0) drain lands ~1000cy
// after issue = free).  Single acc (no ping-pong), STATS after MFMA, no gate/setprio.
__global__ __launch_bounds__(256, 3) void k_main(const unsigned short* __restrict__ srcb,
                                                 const unsigned short* __restrict__ tgtb,
                                                 const int* __restrict__ classes,
                                                 float* __restrict__ pm,
                                                 float* __restrict__ ps) {
  __shared__ uint4 sB[2][1024];               // 2 x 16KB B-tile buffers

  // decode: b = p&3 (one batch per XCD under p%8 round-robin), jl = bit2 (XCD pairs
  // split the chunk space), rb = CU slot, top = residency generation -> j.
  const int p   = blockIdx.x;
  const int b   = p & 3;
  const int jl  = (p >> 2) & 1;
  const int rb  = (p >> 3) & 31;
  const int top = p >> 8;                     // 0..2
  const int j   = top * 2 + jl;               // 0..5
  const int t0  = (j * 64) / 3;               // 32-col tile range [t0, t1) of 128
  const int t1  = ((j + 1) * 64) / 3;         // chunks: 21,21,22,21,21,22
  const int nt  = t1 - t0;

  const int tid  = threadIdx.x;
  const int w    = tid >> 6;                  // wave 0..3 -> rowgroup
  const int lane = tid & 63;
  const int q = lane >> 4, l4 = lane & 15;
  const int rowstart = b * NPATCH + rb * 128 + w * 32;

  // ---- A fragments: 32 rows resident per wave (16 coalesced uint4 loads)
  const uint4* ap = (const uint4*)srcb + (size_t)(b * 256 + rb * 8 + w * 2) * 512 + lane;
  uint4 afr[2][8];
#pragma unroll
  for (int rt = 0; rt < 2; ++rt)
#pragma unroll
    for (int ks = 0; ks < 8; ++ks)
      afr[rt][ks] = ap[rt * 512 + ks * 64];

  int rcls[2][4];
#pragma unroll
  for (int rt = 0; rt < 2; ++rt)
#pragma unroll
    for (int r = 0; r < 4; ++r)
      rcls[rt][r] = classes[rowstart + rt * 16 + q * 4 + r];

  float m_[2][4], s_[2][4];
#pragma unroll
  for (int rt = 0; rt < 2; ++rt)
#pragma unroll
    for (int r = 0; r < 4; ++r) { m_[rt][r] = -INFINITY; s_[rt][r] = 0.f; }

  // ---- staging source: per-lane address; wave w covers 16B-chunks {r*4+w}
  const uint4* bstage = (const uint4*)tgtb + (size_t)(b * 256 + t0 * 2) * 512
                      + w * 64 + lane;
  const int* clp = classes + b * NPATCH + t0 * 32 + (w & 1) * 0 + l4;  // cols of tile

#define STAGE(NB, IT)                                                               \
  {                                                                                 \
    const uint4* g = bstage + (size_t)(IT) * 1024;                                  \
    _Pragma("unroll")                                                               \
    for (int r = 0; r < 4; ++r)                                                     \
      glds16(g + r * 256, &sB[NB][(r * 4 + w) * 64]);                               \
  }

#define STATS(ac, cc0, cc1)                                                         \
  {                                                                                 \
    _Pragma("unroll")                                                               \
    for (int rt = 0; rt < 2; ++rt) {                                                \
      _Pragma("unroll")                                                             \
      for (int r = 0; r < 4; ++r) {                                                 \
        int rc = rcls[rt][r];                                                       \
        float y0 = ((cc0) == rc) ? NEGH : (ac)[rt][0][r];                           \
        float y1 = ((cc1) == rc) ? NEGH : (ac)[rt][1][r];                           \
        float nm = fmaxf(m_[rt][r], fmaxf(y0, y1));                                 \
        float e01 = fexp2(y0 - nm) + fexp2(y1 - nm);                                \
        s_[rt][r] = fmaf(s_[rt][r], fexp2(m_[rt][r] - nm), e01);                    \
        m_[rt][r] = nm;                                                             \
      }                                                                             \
    }                                                                               \
  }

  const f32x4 zc = {0.f, 0.f, 0.f, 0.f};

  STAGE(0, 0);                                // prologue: tile 0 -> buf 0
  __syncthreads();                            // implicit vmcnt(0) drain

  int cb = 0;
  for (int it = 0; it < nt; ++it) {
    if (it + 1 < nt) STAGE(cb ^ 1, it + 1);   // prefetch next tile (drained at barrier)

    int c0 = clp[0];                          // this tile's column classes
    int c1 = clp[16];
    clp += 32;

    f32x4 acc[2][2];
    {                                         // kh = 0
      uint4 e0[4], e1[4];
#pragma unroll
      for (int i = 0; i < 4; ++i) {
        e0[i] = sB[cb][i * 64 + lane];
        e1[i] = sB[cb][512 + i * 64 + lane];
      }
#pragma unroll
      for (int ksl = 0; ksl < 4; ++ksl) {
        short8 b0 = __builtin_bit_cast(short8, e0[ksl]);
        short8 b1 = __builtin_bit_cast(short8, e1[ksl]);
#pragma unroll
        for (int rt = 0; rt < 2; ++rt) {
          short8 a = __builtin_bit_cast(short8, afr[rt][ksl]);
          acc[rt][0] = __builtin_amdgcn_mfma_f32_16x16x32_bf16(
              a, b0, (ksl == 0) ? zc : acc[rt][0], 0, 0, 0);
          acc[rt][1] = __builtin_amdgcn_mfma_f32_16x16x32_bf16(
              a, b1, (ksl == 0) ? zc : acc[rt][1], 0, 0, 0);
        }
      }
    }
    {                                         // kh = 1
      uint4 e0[4], e1[4];
#pragma unroll
      for (int i = 0; i < 4; ++i) {
        e0[i] = sB[cb][256 + i * 64 + lane];
        e1[i] = sB[cb][768 + i * 64 + lane];
      }
#pragma unroll
      for (int ksl = 0; ksl < 4; ++ksl) {
        short8 b0 = __builtin_bit_cast(short8, e0[ksl]);
        short8 b1 = __builtin_bit_cast(short8, e1[ksl]);
#pragma unroll
        for (int rt = 0; rt < 2; ++rt) {
          short8 a = __builtin_bit_cast(short8, afr[rt][4 + ksl]);
          acc[rt][0] = __builtin_amdgcn_mfma_f32_16x16x32_bf16(a, b0, acc[rt][0], 0, 0, 0);
          acc[rt][1] = __builtin_amdgcn_mfma_f32_16x16x32_bf16(a, b1, acc[rt][1], 0, 0, 0);
        }
      }
    }

    STATS(acc, c0, c1);

    if (it + 1 < nt) { __syncthreads(); cb ^= 1; }
  }
#undef STAGE
#undef STATS

  // butterfly merge across the 16 col-lanes of each quad
#pragma unroll
  for (int off = 1; off < 16; off <<= 1) {
#pragma unroll
    for (int rt = 0; rt < 2; ++rt)
#pragma unroll
      for (int r = 0; r < 4; ++r) {
        float om = __shfl_xor(m_[rt][r], off, 64);
        float os = __shfl_xor(s_[rt][r], off, 64);
        float nm = fmaxf(m_[rt][r], om);
        s_[rt][r] = s_[rt][r] * fexp2(m_[rt][r] - nm) + os * fexp2(om - nm);
        m_[rt][r] = nm;
      }
  }

  if (l4 == 0) {
#pragma unroll
    for (int rt = 0; rt < 2; ++rt)
#pragma unroll
      for (int r = 0; r < 4; ++r) {
        size_t o = (size_t)j * NROWS + rowstart + rt * 16 + q * 4 + r;
        pm[o] = m_[rt][r];                     // log2 domain
        ps[o] = s_[rt][r];
      }
  }
}

// ---------------- final: merge chunk partials + pad term + scatter (grid 64) ----------
__global__ __launch_bounds__(256) void k_fin(const int* __restrict__ classes,
                                             const float* __restrict__ pos,
                                             const float* __restrict__ pm,
                                             const float* __restrict__ ps,
                                             const int* __restrict__ outpos,
                                             const int* __restrict__ counts,
                                             float* __restrict__ out) {
  int n = blockIdx.x * 256 + threadIdx.x;
  int b = n >> 12;
  int c = classes[n];
  float ps_ = pos[n];

  float M2 = -INFINITY;
  float mm[NCHUNK], ss[NCHUNK];
#pragma unroll
  for (int s = 0; s < NCHUNK; ++s) {
    mm[s] = pm[(size_t)s * NROWS + n];
    ss[s] = ps[(size_t)s * NROWS + n];
    M2 = fmaxf(M2, mm[s]);
  }
  float S2 = 0.f;
#pragma unroll
  for (int s = 0; s < NCHUNK; ++s) S2 = fmaf(ss[s], fexp2(mm[s] - M2), S2);
  float ln = (S2 > 0.f) ? (M2 + flog2(S2)) * LN2F : -INFINITY;

  int npad = counts[b * MAXC + c] - 1;
  float pt = (npad > 0) ? (logf((float)npad) + NEGFILL_T) : -INFINITY;
  float M = fmaxf(ps_, fmaxf(ln, pt));
  float lse = M + logf(expf(ps_ - M) + expf(ln - M) + expf(pt - M));
  out[b * NPATCH + outpos[n]] = lse - ps_;
}

extern "C" void kernel_launch(void* const* d_in, const int* in_sizes, int n_in,
                              void* d_out, int out_size, void* d_ws, size_t ws_size,
                              hipStream_t stream) {
  const float* src = (const float*)d_in[0];
  const float* tgt = (const float*)d_in[1];
  const int* cls   = (const int*)d_in[2];
  float* out = (float*)d_out;

  char* ws = (char*)d_ws;
  unsigned short* tgtb = (unsigned short*)(ws);            //  8,388,608 B (fragment layout)
  unsigned short* srcb = (unsigned short*)(ws + 8388608);  //  8,388,608 B (frag, pre-scaled)
  float* pos    = (float*)(ws + 16777216);                 //     65,536 B
  float* pm     = (float*)(ws + 16842752);                 //    393,216 B (6 chunk planes)
  float* ps     = (float*)(ws + 17235968);                 //    393,216 B
  int*   outpos = (int*)  (ws + 17629184);                 //     65,536 B
  int*   counts = (int*)  (ws + 17694720);                 //         80 B

  k_aux<<<512 + NBATCH, 256, 0, stream>>>(src, tgt, cls, tgtb, srcb, pos, outpos, counts);
  k_main<<<GRID_MAIN, 256, 0, stream>>>(srcb, tgtb, cls, pm, ps);
  k_fin<<<NROWS / 256, 256, 0, stream>>>(cls, pos, pm, ps, outpos, counts, out);
}

// Round 6
// 127.204 us; speedup vs baseline: 1.0538x; 1.0053x over previous
//
#include <hip/hip_runtime.h>
#include <cstdint>

#define NBATCH 4
#define NPATCH 4096
#define MAXC   5
#define NCHUNK 6                            /* col chunks (j) */
#define RBLOCKS 32                          /* 128-row blocks per batch */
#define GRID_MAIN (NBATCH * RBLOCKS * NCHUNK)   /* 768 4-wave blocks = 3/CU */
#define SCALE  14.285714285714286f          /* 1/T, T=0.07 */
#define SCALE2 20.609929006188747f          /* (1/T) * log2(e) */
#define LN2F   0.6931471805599453f
#define NEGH  -1.0e38f
#define NEGFILL_T -142.85714285714286f      /* NEG_FILL / T */
#define NROWS (NBATCH * NPATCH)

typedef __attribute__((ext_vector_type(8))) short short8;   // 8 bf16 (4 VGPRs)
typedef __attribute__((ext_vector_type(4))) float f32x4;
typedef __attribute__((ext_vector_type(4))) unsigned int u32x4;

__device__ __forceinline__ float fexp2(float x) { return __builtin_amdgcn_exp2f(x); }
__device__ __forceinline__ float flog2(float x) { return __builtin_amdgcn_logf(x); }  // v_log_f32 = log2

__device__ __forceinline__ unsigned short f2bf(float f) {
  uint32_t u = __builtin_bit_cast(uint32_t, f);
  u = (u + 0x7FFFu + ((u >> 16) & 1u)) >> 16;   // RNE
  return (unsigned short)u;
}

// async global->LDS, 16B per lane; LDS dest is wave-uniform base + lane*16
__device__ __forceinline__ void glds16(const void* g, void* l) {
  __builtin_amdgcn_global_load_lds(
      (const __attribute__((address_space(1))) uint32_t*)g,
      (__attribute__((address_space(3))) uint32_t*)l, 16, 0, 0);
}

// Fragment layout (srcb and tgtb): tile = 16 rows x 256 k (8 KB).
// 16B chunk (8 bf16, one row's k-octet) at uint4 index  tile*512 + kc*16 + row16
// (kc = k/8, row16 = row%16).  A wave's fragment read (kc = ks*4+q, row = l4,
// lane = q*16+l4) is  base + ks*64 + lane : contiguous 1KB per instruction.

// ---- k_aux: 2 roles ----  (unchanged)
__global__ __launch_bounds__(256) void k_aux(const float* __restrict__ src,
                                             const float* __restrict__ tgt,
                                             const int* __restrict__ classes,
                                             unsigned short* __restrict__ tgtb,
                                             unsigned short* __restrict__ srcb,
                                             float* __restrict__ pos,
                                             int* __restrict__ outpos,
                                             int* __restrict__ counts) {
  int blk = blockIdx.x;
  if (blk < 512) {
    int t  = threadIdx.x;
    int tl = blk * 2 + (t >> 7);
    int tt = t & 127;
    int row16 = tt >> 3;
    int kg    = tt & 7;
    size_t rowbase = (size_t)(tl * 16 + row16) * 256 + kg * 32;
    const float4* rs = (const float4*)(src + rowbase);
    const float4* rt_ = (const float4*)(tgt + rowbase);
    uint4* wsrc = (uint4*)srcb + (size_t)tl * 512 + (size_t)(kg * 4) * 16 + row16;
    uint4* wtgt = (uint4*)tgtb + (size_t)tl * 512 + (size_t)(kg * 4) * 16 + row16;
    float d = 0.f;
#pragma unroll
    for (int j = 0; j < 4; ++j) {
      float4 sa = rs[j * 2], sb = rs[j * 2 + 1];
      float4 ta = rt_[j * 2], tb = rt_[j * 2 + 1];
      d += sa.x * ta.x + sa.y * ta.y + sa.z * ta.z + sa.w * ta.w
         + sb.x * tb.x + sb.y * tb.y + sb.z * tb.z + sb.w * tb.w;
      union { ushort4 h[2]; uint4 u; } pk;
      pk.h[0].x = f2bf(sa.x * SCALE2); pk.h[0].y = f2bf(sa.y * SCALE2);
      pk.h[0].z = f2bf(sa.z * SCALE2); pk.h[0].w = f2bf(sa.w * SCALE2);
      pk.h[1].x = f2bf(sb.x * SCALE2); pk.h[1].y = f2bf(sb.y * SCALE2);
      pk.h[1].z = f2bf(sb.z * SCALE2); pk.h[1].w = f2bf(sb.w * SCALE2);
      wsrc[j * 16] = pk.u;
      pk.h[0].x = f2bf(ta.x); pk.h[0].y = f2bf(ta.y);
      pk.h[0].z = f2bf(ta.z); pk.h[0].w = f2bf(ta.w);
      pk.h[1].x = f2bf(tb.x); pk.h[1].y = f2bf(tb.y);
      pk.h[1].z = f2bf(tb.z); pk.h[1].w = f2bf(tb.w);
      wtgt[j * 16] = pk.u;
    }
    d += __shfl_xor(d, 1, 64);
    d += __shfl_xor(d, 2, 64);
    d += __shfl_xor(d, 4, 64);
    if (kg == 0) pos[tl * 16 + row16] = d * SCALE;
    return;
  }

  __shared__ int sa[MAXC * 256];
  __shared__ int sb2[MAXC * 256];
  int b = blk - 512, t = threadIdx.x;
  int base = b * NPATCH + t * 16;
  int cv[16];
#pragma unroll
  for (int e = 0; e < 16; ++e) cv[e] = classes[base + e];
  int cnt[MAXC];
#pragma unroll
  for (int c = 0; c < MAXC; ++c) {
    cnt[c] = 0;
#pragma unroll
    for (int e = 0; e < 16; ++e)
      if (cv[e] == c) cnt[c]++;
  }
#pragma unroll
  for (int c = 0; c < MAXC; ++c) sa[c * 256 + t] = cnt[c];
  __syncthreads();

  int* rp = sa; int* wp = sb2;
  for (int d = 1; d < 256; d <<= 1) {
#pragma unroll
    for (int c = 0; c < MAXC; ++c) {
      int v = rp[c * 256 + t];
      if (t >= d) v += rp[c * 256 + t - d];
      wp[c * 256 + t] = v;
    }
    __syncthreads();
    int* tmp = rp; rp = wp; wp = tmp;
  }

  int tot[MAXC], excl[MAXC], off[MAXC + 1];
  off[0] = 0;
#pragma unroll
  for (int c = 0; c < MAXC; ++c) {
    tot[c]  = rp[c * 256 + 255];
    excl[c] = rp[c * 256 + t] - cnt[c];
    off[c + 1] = off[c] + tot[c];
  }
#pragma unroll
  for (int c = 0; c < MAXC; ++c) {
    int r = off[c] + excl[c];
#pragma unroll
    for (int e = 0; e < 16; ++e)
      if (cv[e] == c) { outpos[base + e] = r; r++; }
  }
  if (t < MAXC) counts[b * MAXC + t] = tot[t];
}

// ---------------- main fused GEMM + online lse stats -----------------------------------
// R5: PIN the A fragments.  R4's VGPR_Count=68 < 64 regs of declared afr[2][8] proves
// the compiler rematerialized the A-fragment global loads INSIDE the K-loop: 16KB/wave/
// iter of hidden TCP traffic (1.05GB total == the B traffic R4 removed) -- explains the
// session-long ~50us invariance.  Fix: empty asm "+v" on each afr value after load makes
// it opaque (remat impossible; must stay in VGPRs).  Budget ~150 regs < 168 (3 blk/CU).
// Everything else identical to R4 (LDS-shared double-buffered B, STATS after MFMA).
__global__ __launch_bounds__(256, 3) void k_main(const unsigned short* __restrict__ srcb,
                                                 const unsigned short* __restrict__ tgtb,
                                                 const int* __restrict__ classes,
                                                 float* __restrict__ pm,
                                                 float* __restrict__ ps) {
  __shared__ u32x4 sB[2][1024];               // 2 x 16KB B-tile buffers

  // decode: b = p&3 (one batch per XCD under p%8 round-robin), jl = bit2 (XCD pairs
  // split the chunk space), rb = CU slot, top = residency generation -> j.
  const int p   = blockIdx.x;
  const int b   = p & 3;
  const int jl  = (p >> 2) & 1;
  const int rb  = (p >> 3) & 31;
  const int top = p >> 8;                     // 0..2
  const int j   = top * 2 + jl;               // 0..5
  const int t0  = (j * 64) / 3;               // 32-col tile range [t0, t1) of 128
  const int t1  = ((j + 1) * 64) / 3;         // chunks: 21,21,22,21,21,22
  const int nt  = t1 - t0;

  const int tid  = threadIdx.x;
  const int w    = tid >> 6;                  // wave 0..3 -> rowgroup
  const int lane = tid & 63;
  const int q = lane >> 4, l4 = lane & 15;
  const int rowstart = b * NPATCH + rb * 128 + w * 32;

  // ---- A fragments: 32 rows resident per wave (16 coalesced uint4 loads), PINNED
  const u32x4* ap = (const u32x4*)srcb + (size_t)(b * 256 + rb * 8 + w * 2) * 512 + lane;
  u32x4 afr[2][8];
#pragma unroll
  for (int rt = 0; rt < 2; ++rt)
#pragma unroll
    for (int ks = 0; ks < 8; ++ks)
      afr[rt][ks] = ap[rt * 512 + ks * 64];
#pragma unroll
  for (int rt = 0; rt < 2; ++rt)
#pragma unroll
    for (int ks = 0; ks < 8; ++ks)
      asm volatile("" : "+v"(afr[rt][ks]));   // opaque: no remat, stays in VGPRs

  int rcls[2][4];
#pragma unroll
  for (int rt = 0; rt < 2; ++rt)
#pragma unroll
    for (int r = 0; r < 4; ++r) {
      rcls[rt][r] = classes[rowstart + rt * 16 + q * 4 + r];
      asm volatile("" : "+v"(rcls[rt][r]));
    }

  float m_[2][4], s_[2][4];
#pragma unroll
  for (int rt = 0; rt < 2; ++rt)
#pragma unroll
    for (int r = 0; r < 4; ++r) { m_[rt][r] = -INFINITY; s_[rt][r] = 0.f; }

  // ---- staging source: per-lane address; wave w covers 16B-chunks {r*4+w}
  const u32x4* bstage = (const u32x4*)tgtb + (size_t)(b * 256 + t0 * 2) * 512
                      + w * 64 + lane;
  const int* clp = classes + b * NPATCH + t0 * 32 + l4;

#define STAGE(NB, IT)                                                               \
  {                                                                                 \
    const u32x4* g = bstage + (size_t)(IT) * 1024;                                  \
    _Pragma("unroll")                                                               \
    for (int r = 0; r < 4; ++r)                                                     \
      glds16(g + r * 256, &sB[NB][(r * 4 + w) * 64]);                               \
  }

#define STATS(ac, cc0, cc1)                                                         \
  {                                                                                 \
    _Pragma("unroll")                                                               \
    for (int rt = 0; rt < 2; ++rt) {                                                \
      _Pragma("unroll")                                                             \
      for (int r = 0; r < 4; ++r) {                                                 \
        int rc = rcls[rt][r];                                                       \
        float y0 = ((cc0) == rc) ? NEGH : (ac)[rt][0][r];                           \
        float y1 = ((cc1) == rc) ? NEGH : (ac)[rt][1][r];                           \
        float nm = fmaxf(m_[rt][r], fmaxf(y0, y1));                                 \
        float e01 = fexp2(y0 - nm) + fexp2(y1 - nm);                                \
        s_[rt][r] = fmaf(s_[rt][r], fexp2(m_[rt][r] - nm), e01);                    \
        m_[rt][r] = nm;                                                             \
      }                                                                             \
    }                                                                               \
  }

  const f32x4 zc = {0.f, 0.f, 0.f, 0.f};

  STAGE(0, 0);                                // prologue: tile 0 -> buf 0
  __syncthreads();                            // implicit vmcnt(0) drain

  int cb = 0;
  for (int it = 0; it < nt; ++it) {
    if (it + 1 < nt) STAGE(cb ^ 1, it + 1);   // prefetch next tile (drained at barrier)

    int c0 = clp[0];                          // this tile's column classes
    int c1 = clp[16];
    clp += 32;

    f32x4 acc[2][2];
    {                                         // kh = 0
      u32x4 e0[4], e1[4];
#pragma unroll
      for (int i = 0; i < 4; ++i) {
        e0[i] = sB[cb][i * 64 + lane];
        e1[i] = sB[cb][512 + i * 64 + lane];
      }
#pragma unroll
      for (int ksl = 0; ksl < 4; ++ksl) {
        short8 b0 = __builtin_bit_cast(short8, e0[ksl]);
        short8 b1 = __builtin_bit_cast(short8, e1[ksl]);
#pragma unroll
        for (int rt = 0; rt < 2; ++rt) {
          short8 a = __builtin_bit_cast(short8, afr[rt][ksl]);
          acc[rt][0] = __builtin_amdgcn_mfma_f32_16x16x32_bf16(
              a, b0, (ksl == 0) ? zc : acc[rt][0], 0, 0, 0);
          acc[rt][1] = __builtin_amdgcn_mfma_f32_16x16x32_bf16(
              a, b1, (ksl == 0) ? zc : acc[rt][1], 0, 0, 0);
        }
      }
    }
    {                                         // kh = 1
      u32x4 e0[4], e1[4];
#pragma unroll
      for (int i = 0; i < 4; ++i) {
        e0[i] = sB[cb][256 + i * 64 + lane];
        e1[i] = sB[cb][768 + i * 64 + lane];
      }
#pragma unroll
      for (int ksl = 0; ksl < 4; ++ksl) {
        short8 b0 = __builtin_bit_cast(short8, e0[ksl]);
        short8 b1 = __builtin_bit_cast(short8, e1[ksl]);
#pragma unroll
        for (int rt = 0; rt < 2; ++rt) {
          short8 a = __builtin_bit_cast(short8, afr[rt][4 + ksl]);
          acc[rt][0] = __builtin_amdgcn_mfma_f32_16x16x32_bf16(a, b0, acc[rt][0], 0, 0, 0);
          acc[rt][1] = __builtin_amdgcn_mfma_f32_16x16x32_bf16(a, b1, acc[rt][1], 0, 0, 0);
        }
      }
    }

    STATS(acc, c0, c1);

    if (it + 1 < nt) { __syncthreads(); cb ^= 1; }
  }
#undef STAGE
#undef STATS

  // butterfly merge across the 16 col-lanes of each quad
#pragma unroll
  for (int off = 1; off < 16; off <<= 1) {
#pragma unroll
    for (int rt = 0; rt < 2; ++rt)
#pragma unroll
      for (int r = 0; r < 4; ++r) {
        float om = __shfl_xor(m_[rt][r], off, 64);
        float os = __shfl_xor(s_[rt][r], off, 64);
        float nm = fmaxf(m_[rt][r], om);
        s_[rt][r] = s_[rt][r] * fexp2(m_[rt][r] - nm) + os * fexp2(om - nm);
        m_[rt][r] = nm;
      }
  }

  if (l4 == 0) {
#pragma unroll
    for (int rt = 0; rt < 2; ++rt)
#pragma unroll
      for (int r = 0; r < 4; ++r) {
        size_t o = (size_t)j * NROWS + rowstart + rt * 16 + q * 4 + r;
        pm[o] = m_[rt][r];                     // log2 domain
        ps[o] = s_[rt][r];
      }
  }
}

// ---------------- final: merge chunk partials + pad term + scatter (grid 64) ----------
__global__ __launch_bounds__(256) void k_fin(const int* __restrict__ classes,
                                             const float* __restrict__ pos,
                                             const float* __restrict__ pm,
                                             const float* __restrict__ ps,
                                             const int* __restrict__ outpos,
                                             const int* __restrict__ counts,
                                             float* __restrict__ out) {
  int n = blockIdx.x * 256 + threadIdx.x;
  int b = n >> 12;
  int c = classes[n];
  float ps_ = pos[n];

  float M2 = -INFINITY;
  float mm[NCHUNK], ss[NCHUNK];
#pragma unroll
  for (int s = 0; s < NCHUNK; ++s) {
    mm[s] = pm[(size_t)s * NROWS + n];
    ss[s] = ps[(size_t)s * NROWS + n];
    M2 = fmaxf(M2, mm[s]);
  }
  float S2 = 0.f;
#pragma unroll
  for (int s = 0; s < NCHUNK; ++s) S2 = fmaf(ss[s], fexp2(mm[s] - M2), S2);
  float ln = (S2 > 0.f) ? (M2 + flog2(S2)) * LN2F : -INFINITY;

  int npad = counts[b * MAXC + c] - 1;
  float pt = (npad > 0) ? (logf((float)npad) + NEGFILL_T) : -INFINITY;
  float M = fmaxf(ps_, fmaxf(ln, pt));
  float lse = M + logf(expf(ps_ - M) + expf(ln - M) + expf(pt - M));
  out[b * NPATCH + outpos[n]] = lse - ps_;
}

extern "C" void kernel_launch(void* const* d_in, const int* in_sizes, int n_in,
                              void* d_out, int out_size, void* d_ws, size_t ws_size,
                              hipStream_t stream) {
  const float* src = (const float*)d_in[0];
  const float* tgt = (const float*)d_in[1];
  const int* cls   = (const int*)d_in[2];
  float* out = (float*)d_out;

  char* ws = (char*)d_ws;
  unsigned short* tgtb = (unsigned short*)(ws);            //  8,388,608 B (fragment layout)
  unsigned short* srcb = (unsigned short*)(ws + 8388608);  //  8,388,608 B (frag, pre-scaled)
  float* pos    = (float*)(ws + 16777216);                 //     65,536 B
  float* pm     = (float*)(ws + 16842752);                 //    393,216 B (6 chunk planes)
  float* ps     = (float*)(ws + 17235968);                 //    393,216 B
  int*   outpos = (int*)  (ws + 17629184);                 //     65,536 B
  int*   counts = (int*)  (ws + 17694720);                 //         80 B

  k_aux<<<512 + NBATCH, 256, 0, stream>>>(src, tgt, cls, tgtb, srcb, pos, outpos, counts);
  k_main<<<GRID_MAIN, 256, 0, stream>>>(srcb, tgtb, cls, pm, ps);
  k_fin<<<NROWS / 256, 256, 0, stream>>>(cls, pos, pm, ps, outpos, counts, out);
}